// Round 3
// baseline (321.752 us; speedup 1.0000x reference)
//
#include <hip/hip_runtime.h>
#include <hip/hip_bf16.h>

typedef __attribute__((ext_vector_type(8))) short s16x8;
typedef __attribute__((ext_vector_type(4))) short s16x4;
typedef __attribute__((ext_vector_type(4))) float f32x4;
typedef unsigned short u16;

// ---------------- workspace layout (bytes), total <= 41,943,040 (proven) ----------------
#define WS_FWD    0            // 384 int
#define WS_INV    2048         // 384 int (inverse perm: inv[c] = o)
#define WS_SCALE  4096         // 384 f32
#define WS_OFFS   6144         // 384 f32
#define WS_WHI    8192         // packed w_hi bf16: 4*6*384*32*2 = 589,824 B -> ends 598,016
#define WS_XD     2097152      // xd = down(x1) (b,h,w,192) bf16 = 12,582,912 B
#define WS_WLO    14680064     // packed w_lo bf16: 9*6*384*32*2 = 1,327,104 B -> ends 16,007,168
#define WS_Y2     16777216     // y2' (b,h,w,192) bf16 = 12,582,912 B -> ends 29,360,128

static __device__ __forceinline__ u16 f2bf(float f) {
    __hip_bfloat16 h = __float2bfloat16(f);
    return *reinterpret_cast<u16*>(&h);
}
static __device__ __forceinline__ float bf2f(u16 u) {
    __hip_bfloat16 h = *reinterpret_cast<__hip_bfloat16*>(&u);
    return __bfloat162float(h);
}

// ---------------- prep: perm index (fwd + inv) + scale/offset ----------------
__global__ __launch_bounds__(256)
void k_prep0(const float* __restrict__ pw, const float* __restrict__ an,
             const float* __restrict__ ao, int* __restrict__ fwd,
             int* __restrict__ inv, float* __restrict__ scale,
             float* __restrict__ offs)
{
    int o = blockIdx.x * 256 + threadIdx.x;
    if (o >= 384) return;
    int f = 0;
    for (int c = 0; c < 384; ++c)
        if (pw[(size_t)o * 384 + c] > 0.5f) f = c;
    fwd[o]   = f;
    inv[f]   = o;
    scale[o] = 0.2f * log1pf(expf(0.5f * an[o]));
    offs[o]  = ao[o];
}

// ---------------- pack w_hi into bf16 MFMA B-fragment layout ----------------
__global__ __launch_bounds__(256)
void k_pack_hi(const float* __restrict__ w, u16* __restrict__ wp)
{
    int gid = blockIdx.x * 256 + threadIdx.x;   // 294,912 exact (1152 blocks)
    int c32 = gid & 31;
    int n   = (gid >> 5) % 384;
    int tkc = gid / (384 * 32);
    int kc  = tkc % 6;
    int t   = tkc / 6;
    int c   = kc * 32 + c32;
    int th = t >> 1, tw = t & 1;
    int cin = c >> 2, dy = (c >> 1) & 1, dx = c & 1;
    float wv = 0.f;
    if (!(th == 0 && dy == 0) && !(tw == 0 && dx == 0)) {
        int ky = (th == 0) ? 0 : 1 + dy;
        int kx = (tw == 0) ? 0 : 1 + dx;
        wv = w[(((size_t)n * 48 + cin) * 3 + ky) * 3 + kx];
    }
    wp[gid] = f2bf(wv);
}

// ---------------- pack w_lo into bf16 MFMA B-fragment layout ----------------
__global__ __launch_bounds__(256)
void k_pack_lo(const float* __restrict__ w, u16* __restrict__ wp)
{
    int gid = blockIdx.x * 256 + threadIdx.x;   // 663,552 exact (2592 blocks)
    int c32 = gid & 31;
    int n   = (gid >> 5) % 384;
    int tkc = gid / (384 * 32);
    int kc  = tkc % 6;
    int t   = tkc / 6;
    int c   = kc * 32 + c32;
    wp[gid] = f2bf(w[((size_t)n * 192 + c) * 9 + t]);
}

// ---------------- X1d: down(x1) to (b,h,w,192) bf16 — 2 channels/thread ----------------
__global__ __launch_bounds__(256)
void k_xd(const float* __restrict__ x, u16* __restrict__ xd)
{
    int gid = blockIdx.x * 256 + threadIdx.x;   // 3,145,728 exact (12288 blocks)
    int pix = gid / 96;
    int j = gid - pix * 96;                     // channel pair: c0 = 2j (dx = 0,1)
    int b = pix >> 10, h = (pix >> 5) & 31, w = pix & 31;
    int c0 = j * 2;
    int cin = c0 >> 2, dy = (c0 >> 1) & 1;
    float2 v = *(const float2*)&x[(((size_t)b * 96 + cin) * 64 + (2 * h + dy)) * 64 + 2 * w];
    unsigned lo = f2bf(v.x), hi = f2bf(v.y);
    *(unsigned*)&xd[(size_t)pix * 192 + c0] = lo | (hi << 16);
}

// ---------------- fused MFMA gemm + affine + permuted-output epilogue ----------------
// Main loop: flattened (t,kc) step loop with explicit double-buffered fragment prefetch.
// Epilogue: a_lds channel-major [384][68]; w-major affine pass (lane = pixel, c uniform)
//   -> LDS-broadcast a reads, semi-coalesced x gathers, FULLY COALESCED permuted out stores.
// T=4 additionally stashes y2' bf16 into consumed a_lds rows, re-emits pixel-major.
template <int T>
__global__ __launch_bounds__(256)
void f_gemm(const u16* __restrict__ in_t, const u16* __restrict__ wpk,
            const float* __restrict__ bias, const float* __restrict__ x,
            const int* __restrict__ inv, const float* __restrict__ scale,
            const float* __restrict__ offs, u16* __restrict__ y2out,
            float* __restrict__ out)
{
    const int tid = threadIdx.x;
    const int lane = tid & 63;
    const int wave = tid >> 6;
    const int l16 = lane & 15;
    const int quad = lane >> 4;
    const int mblk = blockIdx.x;           // 512 blocks
    const int b = mblk >> 4;
    const int h0 = (mblk & 15) << 1;
    const int n0 = wave * 96;

    __shared__ u16 a_lds[384 * 68];        // channel-major, stride 68 u16 (136 B rows); 52,224 B

    const f32x4 zero4 = {0.f, 0.f, 0.f, 0.f};
    f32x4 acc[4][6];
#pragma unroll
    for (int a = 0; a < 4; ++a)
#pragma unroll
        for (int c = 0; c < 6; ++c) acc[a][c] = zero4;

#define LOADSTEP(s_, bf_, af_) do {                                              \
    int t_ = (s_) / 6, kc_ = (s_) - 6 * t_;                                      \
    int dh_ = (T == 4) ? ((t_ >> 1) - 1) : (t_ / 3 - 1);                         \
    int dw_ = (T == 4) ? ((t_ & 1) - 1) : (t_ % 3 - 1);                          \
    const u16* wp_ = wpk + (size_t)(s_) * (384 * 32);                            \
    _Pragma("unroll")                                                            \
    for (int ns_ = 0; ns_ < 6; ++ns_)                                            \
        bf_[ns_] = *(const s16x8*)(wp_ + (n0 + ns_ * 16 + l16) * 32 + quad * 8); \
    _Pragma("unroll")                                                            \
    for (int ms_ = 0; ms_ < 4; ++ms_) {                                          \
        int m_ = ms_ * 16 + l16;                                                 \
        int ih_ = h0 + (m_ >> 5) + dh_;                                          \
        int iw_ = (m_ & 31) + dw_;                                               \
        s16x8 v_ = {0, 0, 0, 0, 0, 0, 0, 0};                                     \
        if (ih_ >= 0 && ih_ < 32 && iw_ >= 0 && iw_ < 32)                        \
            v_ = *(const s16x8*)(in_t + (((size_t)b * 32 + ih_) * 32 + iw_) * 192 \
                                 + kc_ * 32 + quad * 8);                         \
        af_[ms_] = v_;                                                           \
    }                                                                            \
} while (0)

#define MFMASTEP(bf_, af_) do {                                                  \
    _Pragma("unroll")                                                            \
    for (int ms_ = 0; ms_ < 4; ++ms_)                                            \
        _Pragma("unroll")                                                        \
        for (int ns_ = 0; ns_ < 6; ++ns_)                                        \
            acc[ms_][ns_] = __builtin_amdgcn_mfma_f32_16x16x32_bf16(             \
                af_[ms_], bf_[ns_], acc[ms_][ns_], 0, 0, 0);                     \
} while (0)

    {
        s16x8 bfA[6], afA[4], bfB[6], afB[4];
        LOADSTEP(0, bfA, afA);
        for (int s = 0; s < T * 6; s += 2) {       // T*6 even for T=4,9... (24, 54)
            LOADSTEP(s + 1, bfB, afB);
            MFMASTEP(bfA, afA);
            if (s + 2 < T * 6) LOADSTEP(s + 2, bfA, afA);
            MFMASTEP(bfB, afB);
        }
    }
#undef LOADSTEP
#undef MFMASTEP

    // ---- epilogue phase 1: a = f2bf(acc + bias) -> a_lds[channel][pixel] ----
    // C/D belief: col(N)=lane&15, row(M)=quad*4+reg; 4 consecutive m per reg quad -> b64 write
#pragma unroll
    for (int ms = 0; ms < 4; ++ms) {
#pragma unroll
        for (int ns = 0; ns < 6; ++ns) {
            int n = n0 + ns * 16 + l16;
            float bv = bias[n];
            s16x4 pk;
#pragma unroll
            for (int r4 = 0; r4 < 4; ++r4)
                pk[r4] = (short)f2bf(acc[ms][ns][r4] + bv);
            *(s16x4*)&a_lds[n * 68 + ms * 16 + quad * 4] = pk;
        }
    }
    __syncthreads();

    // ---- epilogue phase A: w-major affine + coalesced permuted out-half ----
    // lane = pixel m (2 rows x 32 w); wave owns channels [wave*48, wave*48+48)
    {
        const int m = lane;
        const int h = h0 + (m >> 5);
        const int w = m & 31;
        for (int i = 0; i < 48; ++i) {
            int c = wave * 48 + i;
            float a_s = bf2f(a_lds[c * 68 + m]);
            float a_o = bf2f(a_lds[(c + 192) * 68 + m]);
            int cin = (T == 4 ? 48 : 0) + (c >> 2);
            float xv = x[(((size_t)b * 96 + cin) * 64 + (2 * h + ((c >> 1) & 1))) * 64
                         + (2 * w + (c & 1))];
            float e = expf(0.4f * a_s);
            float sj = 2.f - 4.f / (e + 1.f);
            float y = xv * expf(sj) + a_o;
            int cg = (T == 4) ? (192 + c) : c;
            int o = inv[cg];
            if (T == 4) {
                u16 yb = f2bf(y);
                a_lds[c * 68 + m] = yb;     // stash y2' (row c fully consumed by this wave)
                out[(((size_t)b * 384 + o) * 32 + h) * 32 + w] =
                    bf2f(yb) * scale[cg] + offs[cg];
            } else {
                out[(((size_t)b * 384 + o) * 32 + h) * 32 + w] =
                    y * scale[cg] + offs[cg];
            }
        }
    }

    // ---- epilogue phase B (T=4 only): emit y2' pixel-major for gemm<9> A-loads ----
    if (T == 4) {
        __syncthreads();
        for (int it = 0; it < 6; ++it) {
            int v = it * 256 + tid;        // 1536 = 64 m x 24 c-octets
            int m2 = v / 24;
            int c8 = v - m2 * 24;
            int c0 = c8 * 8;
            int h2 = h0 + (m2 >> 5);
            int w2 = m2 & 31;
            size_t pix = ((size_t)b * 32 + h2) * 32 + w2;
            s16x8 yv;
#pragma unroll
            for (int j = 0; j < 8; ++j)
                yv[j] = (short)a_lds[(c0 + j) * 68 + m2];
            *(s16x8*)&y2out[pix * 192 + c0] = yv;
        }
    }
}

extern "C" void kernel_launch(void* const* d_in, const int* in_sizes, int n_in,
                              void* d_out, int out_size, void* d_ws, size_t ws_size,
                              hipStream_t stream)
{
    const float* x        = (const float*)d_in[0];
    const float* w_hi     = (const float*)d_in[1];
    const float* b_hi     = (const float*)d_in[2];
    const float* w_lo     = (const float*)d_in[3];
    const float* b_lo     = (const float*)d_in[4];
    const float* act_norm = (const float*)d_in[5];
    const float* act_off  = (const float*)d_in[6];
    const float* perm_w   = (const float*)d_in[7];
    float* out = (float*)d_out;
    char* ws = (char*)d_ws;

    int*   fwd   = (int*)(ws + WS_FWD);
    int*   inv   = (int*)(ws + WS_INV);
    float* scale = (float*)(ws + WS_SCALE);
    float* offs  = (float*)(ws + WS_OFFS);
    u16*   whi   = (u16*)(ws + WS_WHI);
    u16*   xd    = (u16*)(ws + WS_XD);
    u16*   wlo   = (u16*)(ws + WS_WLO);
    u16*   y2    = (u16*)(ws + WS_Y2);

    k_prep0<<<2, 256, 0, stream>>>(perm_w, act_norm, act_off, fwd, inv, scale, offs);
    k_pack_hi<<<1152, 256, 0, stream>>>(w_hi, whi);
    k_pack_lo<<<2592, 256, 0, stream>>>(w_lo, wlo);
    k_xd<<<12288, 256, 0, stream>>>(x, xd);
    f_gemm<4><<<512, 256, 0, stream>>>(xd, whi, b_hi, x, inv, scale, offs, y2, out);
    f_gemm<9><<<512, 256, 0, stream>>>(y2, wlo, b_lo, x, inv, scale, offs, y2, out);
}